// Round 1
// baseline (138.201 us; speedup 1.0000x reference)
//
#include <hip/hip_runtime.h>

// ---------------- workspace layout (bytes) ----------------
#define WS_SACC   0        // f32[32]: S0[c]=0..9, S1=10..19, S2=20..29
#define WS_COUNTS 128      // i32[16]
#define WS_INVCNT 192      // f32[16]
#define WS_INVWN  256      // f32[16]
#define WS_TCLS   320      // i32[64]
#define WS_TVCNT  576      // i32[64]
#define WS_NTILES 832      // i32
#define WS_PERM   1024     // i32[5504] (43 tiles * 128)
#define WS_SQBF   23040    // f32[4096]
#define WS_PROJ   39424    // f32[4096*10]  raw proj (unscaled)
#define WS_PREDBF 203264   // bf16[4096*128] = 1 MB
// total ~1.23 MB

#define NCLS 10
#define NROW 4096
#define DDIM 128
#define MAXTILES 42

typedef __attribute__((ext_vector_type(8))) short short8;
typedef __attribute__((ext_vector_type(4))) float f32x4;

__device__ __forceinline__ unsigned short f2bf(float x) {
  unsigned int u = __float_as_uint(x);
  u += 0x7FFFu + ((u >> 16) & 1u);   // round-nearest-even
  return (unsigned short)(u >> 16);
}
__device__ __forceinline__ float bf2f(unsigned short b) {
  return __uint_as_float(((unsigned int)b) << 16);
}

// ---------------- K1: histogram, wn, class-sorted padded permutation ----------
__global__ void k_setup(const int* __restrict__ tgt, const float* __restrict__ W,
                        char* __restrict__ ws) {
  __shared__ int h[NCLS];
  __shared__ int cursor[NCLS];
  __shared__ int base[NCLS + 1];
  int t = threadIdx.x;
  if (t < NCLS) { h[t] = 0; cursor[t] = 0; }
  __syncthreads();
  for (int j = t; j < NROW; j += 256) atomicAdd(&h[tgt[j]], 1);
  __syncthreads();
  if (t < NCLS) {
    float ss = 0.f;
    for (int k = 0; k < DDIM; k++) { float w = W[t * DDIM + k]; ss = fmaf(w, w, ss); }
    float wn = fmaxf(sqrtf(ss), 1e-8f);
    ((float*)(ws + WS_INVWN))[t] = 1.0f / wn;
    ((int*)(ws + WS_COUNTS))[t] = h[t];
    ((float*)(ws + WS_INVCNT))[t] = 1.0f / (float)max(h[t], 1);
  }
  if (t < 32) ((float*)(ws + WS_SACC))[t] = 0.0f;
  if (t == 0) {
    int nb = 0;
    int* tcls = (int*)(ws + WS_TCLS);
    int* tvc  = (int*)(ws + WS_TVCNT);
    for (int c = 0; c < NCLS; c++) {
      base[c] = nb * 128;
      int tiles = (h[c] + 127) >> 7;
      for (int i = 0; i < tiles; i++) {
        tcls[nb + i] = c;
        tvc[nb + i]  = min(128, h[c] - i * 128);
      }
      nb += tiles;
    }
    base[NCLS] = nb * 128;
    *((int*)(ws + WS_NTILES)) = nb;
  }
  __syncthreads();
  int* perm = (int*)(ws + WS_PERM);
  for (int s = t; s < MAXTILES * 128 + 128; s += 256) perm[s] = 0;  // pads -> safe row 0
  __syncthreads();
  for (int j = t; j < NROW; j += 256) {
    int c = tgt[j];
    int slot = base[c] + atomicAdd(&cursor[c], 1);
    perm[slot] = j;
  }
}

// ---------------- K2: per-row bf16 convert, sumsq(rounded), proj ----------
__global__ void k_rows(const float* __restrict__ pred, const float* __restrict__ W,
                       char* __restrict__ ws) {
  int j = blockIdx.x * 256 + threadIdx.x;
  const float4* p4 = (const float4*)(pred + j * DDIM);
  unsigned short* pb = ((unsigned short*)(ws + WS_PREDBF)) + j * DDIM;
  float ss = 0.f;
  float acc[NCLS];
#pragma unroll
  for (int c = 0; c < NCLS; c++) acc[c] = 0.f;
#pragma unroll 4
  for (int ch = 0; ch < 32; ch++) {
    float4 v = p4[ch];
    unsigned short b0 = f2bf(v.x), b1 = f2bf(v.y), b2 = f2bf(v.z), b3 = f2bf(v.w);
    float r0 = bf2f(b0), r1 = bf2f(b1), r2 = bf2f(b2), r3 = bf2f(b3);
    ss = fmaf(r0, r0, ss); ss = fmaf(r1, r1, ss);
    ss = fmaf(r2, r2, ss); ss = fmaf(r3, r3, ss);
    ushort4 u; u.x = b0; u.y = b1; u.z = b2; u.w = b3;
    *((ushort4*)(pb + ch * 4)) = u;
#pragma unroll
    for (int c = 0; c < NCLS; c++) {
      const float4 w = *(const float4*)(W + c * DDIM + ch * 4);  // uniform -> s_load
      acc[c] = fmaf(v.x, w.x, acc[c]);
      acc[c] = fmaf(v.y, w.y, acc[c]);
      acc[c] = fmaf(v.z, w.z, acc[c]);
      acc[c] = fmaf(v.w, w.w, acc[c]);
    }
  }
  ((float*)(ws + WS_SQBF))[j] = ss;
  float* proj = (float*)(ws + WS_PROJ);
#pragma unroll
  for (int c = 0; c < NCLS; c++) proj[j * NCLS + c] = acc[c];
}

// ---------------- K3: fused G-tile MFMA + pair epilogue ----------
__global__ void __launch_bounds__(256, 2)
k_main(const int* __restrict__ tgt, char* __restrict__ ws) {
  int ntiles = *((const int*)(ws + WS_NTILES));
  int ta = blockIdx.x >> 5;
  int tb = blockIdx.x & 31;
  if (ta >= ntiles) return;

  int cls  = ((const int*)(ws + WS_TCLS))[ta];
  int vcnt = ((const int*)(ws + WS_TVCNT))[ta];
  float invcnt_cls = ((const float*)(ws + WS_INVCNT))[cls];
  float invwn_cls  = ((const float*)(ws + WS_INVWN))[cls];

  __shared__ f32x4 sqa_v[32], pa_v[32], awv_v[32];
  __shared__ float sqb_s[128], pnb_s[128], wvb_s[128];
  __shared__ int   arow_s[128];
  __shared__ float red_s[4][3];

  const float* sqbf   = (const float*)(ws + WS_SQBF);
  const float* proj   = (const float*)(ws + WS_PROJ);
  const int*   perm   = (const int*)(ws + WS_PERM);
  const float* invcnt = (const float*)(ws + WS_INVCNT);
  const unsigned short* predbf = (const unsigned short*)(ws + WS_PREDBF);

  int t = threadIdx.x;
  if (t < 128) {                       // b-side staging (natural row order)
    int b = tb * 128 + t;
    int cb = tgt[b];
    sqb_s[t] = sqbf[b] + 1e-16f;       // fold the +1e-16
    pnb_s[t] = proj[b * NCLS + cls] * invwn_cls;
    wvb_s[t] = (cb != cls) ? invcnt[cb] : 0.0f;
  } else {                             // a-side staging (perm-gathered)
    int i = t - 128;
    int row = perm[ta * 128 + i];
    arow_s[i] = row;
    ((float*)sqa_v)[i] = sqbf[row];
    ((float*)pa_v)[i]  = proj[row * NCLS + cls] * invwn_cls;
    ((float*)awv_v)[i] = (i < vcnt) ? invcnt_cls : 0.0f;   // pads contribute 0
  }
  __syncthreads();

  int lane = t & 63;
  int w    = t >> 6;
  int wr = w >> 1, wc = w & 1;
  int l16 = lane & 15, quad = lane >> 4;

  // A fragments: A[m=lane&15][k=quad*8+j]  (16 frags, held in regs)
  short8 afrag[4][4];
  f32x4 sqa4[4], pa4[4], awv4[4];
#pragma unroll
  for (int fi = 0; fi < 4; fi++) {
    int arow = arow_s[wr * 64 + fi * 16 + l16];
    const unsigned short* ap = predbf + arow * DDIM + quad * 8;
#pragma unroll
    for (int kk = 0; kk < 4; kk++) afrag[fi][kk] = *(const short8*)(ap + kk * 32);
    int vi = wr * 16 + fi * 4 + quad;  // C-layout rows: quad*4+reg
    sqa4[fi] = sqa_v[vi]; pa4[fi] = pa_v[vi]; awv4[fi] = awv_v[vi];
  }

  float S0 = 0.f, S1 = 0.f, S2 = 0.f;
#pragma unroll
  for (int fj = 0; fj < 4; fj++) {
    int brow = tb * 128 + wc * 64 + fj * 16 + l16;   // B[n=lane&15][k=quad*8+j]
    const unsigned short* bp = predbf + brow * DDIM + quad * 8;
    short8 bfrag[4];
#pragma unroll
    for (int kk = 0; kk < 4; kk++) bfrag[kk] = *(const short8*)(bp + kk * 32);
    int bidx = wc * 64 + fj * 16 + l16;
    float sqb = sqb_s[bidx], pnb = pnb_s[bidx], wvb = wvb_s[bidx];
#pragma unroll
    for (int fi = 0; fi < 4; fi++) {
      f32x4 acc = {0.f, 0.f, 0.f, 0.f};
#pragma unroll
      for (int kk = 0; kk < 4; kk++)
        acc = __builtin_amdgcn_mfma_f32_16x16x32_bf16(afrag[fi][kk], bfrag[kk], acc, 0, 0, 0);
#pragma unroll
      for (int r = 0; r < 4; r++) {
        float g  = acc[r];
        float d2 = fmaf(-2.0f, g, sqa4[fi][r] + sqb);
        d2 = fmaxf(d2, 1e-16f);
        float rin = rsqrtf(d2);                 // 1/dn (max with 1e-8 is a no-op)
        float M  = (pa4[fi][r] - pnb) * rin;
        float wg = awv4[fi][r] * wvb;
        S0 += wg;
        float wM = wg * M;
        S1 += wM;
        S2 = fmaf(wM, M, S2);
      }
    }
  }

  // wave butterfly reduce (64 lanes), then block reduce + 3 atomics
#pragma unroll
  for (int off = 32; off > 0; off >>= 1) {
    S0 += __shfl_xor(S0, off, 64);
    S1 += __shfl_xor(S1, off, 64);
    S2 += __shfl_xor(S2, off, 64);
  }
  if (lane == 0) { red_s[w][0] = S0; red_s[w][1] = S1; red_s[w][2] = S2; }
  __syncthreads();
  if (t == 0) {
    float a0 = red_s[0][0] + red_s[1][0] + red_s[2][0] + red_s[3][0];
    float a1 = red_s[0][1] + red_s[1][1] + red_s[2][1] + red_s[3][1];
    float a2 = red_s[0][2] + red_s[1][2] + red_s[2][2] + red_s[3][2];
    float* Sacc = (float*)(ws + WS_SACC);
    atomicAdd(&Sacc[cls], a0);
    atomicAdd(&Sacc[10 + cls], a1);
    atomicAdd(&Sacc[20 + cls], a2);
  }
}

// ---------------- K4: combine ----------
__global__ void k_final(const char* __restrict__ ws, float* __restrict__ out) {
  if (threadIdx.x == 0 && blockIdx.x == 0) {
    const float* Sacc = (const float*)(ws + WS_SACC);
    const int* counts = (const int*)(ws + WS_COUNTS);
    float exist = 0.f;
    for (int c = 0; c < NCLS; c++) if (counts[c] > 0) exist += 1.f;
    float em1 = exist - 1.0f;
    float l1 = 0.f, l2 = 0.f;
    for (int c = 0; c < NCLS; c++) {
      if (counts[c] <= 0) continue;
      float s0 = Sacc[c], s1 = Sacc[10 + c], s2 = Sacc[20 + c];
      l1 += (s0 - 2.f * s1 + s2) / em1;
      float mm = s1 / em1;
      float mv = (s2 - 2.f * mm * s1 + mm * mm * s0) / em1;
      l2 += fabsf(mv / mm);
    }
    out[0] = l1 / exist;
    out[1] = l2 / exist;
  }
}

extern "C" void kernel_launch(void* const* d_in, const int* in_sizes, int n_in,
                              void* d_out, int out_size, void* d_ws, size_t ws_size,
                              hipStream_t stream) {
  const float* pred = (const float*)d_in[0];
  const int*   tgt  = (const int*)d_in[1];
  const float* W    = (const float*)d_in[2];
  float* out = (float*)d_out;
  char*  ws  = (char*)d_ws;

  k_setup<<<1, 256, 0, stream>>>(tgt, W, ws);
  k_rows <<<NROW / 256, 256, 0, stream>>>(pred, W, ws);
  k_main <<<MAXTILES * 32, 256, 0, stream>>>(tgt, ws);
  k_final<<<1, 64, 0, stream>>>(ws, out);
}